// Round 8
// baseline (577.512 us; speedup 1.0000x reference)
//
#include <hip/hip_runtime.h>
#include <math.h>

#define ALPHA 0.3f

constexpr int B  = 32;
constexpr int N  = 100;
constexpr int NF = 128;
constexpr int L  = 3;
constexpr int NN = N * N;            // 10000
constexpr int NPAIR = B * NN;        // 320000
constexpr int PT = 80;               // pairs per block in the fused MFMA MLP

typedef __attribute__((ext_vector_type(8))) short short8;
typedef __attribute__((ext_vector_type(4))) float f32x4;

__device__ __forceinline__ unsigned short f2bf(float x) {
    union { float f; unsigned u; } v; v.f = x;
    unsigned r = v.u + 0x7FFF + ((v.u >> 16) & 1);  // RNE
    return (unsigned short)(r >> 16);
}
__device__ __forceinline__ float bf2f(unsigned short h) {
    union { unsigned u; float f; } v; v.u = ((unsigned)h) << 16;
    return v.f;
}
// packed f32x2 -> bf16x2 (RNE, same rounding as f2bf)
__device__ __forceinline__ unsigned cvt_pk(float lo, float hi) {
    unsigned r;
    asm("v_cvt_pk_bf16_f32 %0, %1, %2" : "=v"(r) : "v"(lo), "v"(hi));
    return r;
}

// ---------------------------------------------------------------------------
// Weight prep, MFMA-fragment order:
// Wp[((l*CT+ct)*KS+ks)*64 + lane][8] = W[l][ks*32+(lane>>4)*8+j][ct*16+(lane&15)] * S
// ---------------------------------------------------------------------------
__global__ void k_wprep_frag(const float* __restrict__ W, const float* __restrict__ S,
                             unsigned short* __restrict__ Wp, int K, int C) {
    const int idx = blockIdx.x * blockDim.x + threadIdx.x;
    const int per = K * C;
    if (idx >= L * per) return;
    const int l = idx / per, r = idx - l * per;
    const int KS = K / 32;
    const int j    = r & 7;
    const int lane = (r >> 3) & 63;
    const int t2   = r >> 9;            // ct*KS + ks
    const int ks = t2 % KS, ct = t2 / KS;
    const int c = ct * 16 + (lane & 15);
    const int k = ks * 32 + (lane >> 4) * 8 + j;
    float v = W[(size_t)l * per + (size_t)k * C + c] * S[l * C + c];
    Wp[idx] = f2bf(v);
}

// ---------------------------------------------------------------------------
// Fused node update: aggr (L1-normalized edge rows x nf) + 2 affine layers.
// 10 rows per block (one batch), 256 threads. Replaces 3 kernels.
// ---------------------------------------------------------------------------
__global__ __launch_bounds__(256) void k_node_fused(
    const float* __restrict__ nf, const float* __restrict__ ef,
    const float* __restrict__ W0, const float* __restrict__ S0, const float* __restrict__ B0,
    const float* __restrict__ W1, const float* __restrict__ S1, const float* __restrict__ B1,
    float* __restrict__ out) {
    __shared__ float nfs[N][NF];       // 51.2 KB
    __shared__ float xr[10][3 * NF];   // 15.36 KB
    __shared__ float hs[10][2 * NF];   // 10.24 KB
    __shared__ float red[4][128];      // 2 KB
    const int t = threadIdx.x;
    const int b = blockIdx.x / 10;
    const int m0 = (blockIdx.x - b * 10) * 10;

    {   // stage nf[b] fully into LDS
        const float4* src = (const float4*)(nf + (size_t)b * N * NF);
        float4* dst = (float4*)&nfs[0][0];
        for (int idx = t; idx < N * NF / 4; idx += 256) dst[idx] = src[idx];
    }
    __syncthreads();

    const int sub = t >> 7, tt = t & 127;
    for (int mm = 0; mm < 10; mm += 2) {
        const int mr = m0 + mm + sub;   // row within batch
        float e0 = 0.f, e1 = 0.f;
        if (tt < N) {
            e0 = ef[((size_t)(b * 2 + 0) * N + mr) * N + tt];
            e1 = ef[((size_t)(b * 2 + 1) * N + mr) * N + tt];
            if (tt == mr) { e0 = 0.f; e1 = 0.f; }
        }
        red[sub * 2 + 0][tt] = fabsf(e0);
        red[sub * 2 + 1][tt] = fabsf(e1);
        __syncthreads();
        for (int s = 64; s > 0; s >>= 1) {
            if (tt < s) {
                red[sub * 2 + 0][tt] += red[sub * 2 + 0][tt + s];
                red[sub * 2 + 1][tt] += red[sub * 2 + 1][tt + s];
            }
            __syncthreads();
        }
        const float s0 = red[sub * 2 + 0][0], s1 = red[sub * 2 + 1][0];
        __syncthreads();
        red[sub * 2 + 0][tt] = (s0 == 0.f) ? 0.f : e0 / s0;
        red[sub * 2 + 1][tt] = (s1 == 0.f) ? 0.f : e1 / s1;
        __syncthreads();
        float a0 = 0.f, a1 = 0.f;
#pragma unroll 4
        for (int n = 0; n < N; ++n) {
            const float v = nfs[n][tt];
            a0 = fmaf(red[sub * 2 + 0][n], v, a0);
            a1 = fmaf(red[sub * 2 + 1][n], v, a1);
        }
        const int lr = mm + sub;
        xr[lr][tt]          = nfs[mr][tt];
        xr[lr][NF + tt]     = a0;
        xr[lr][2 * NF + tt] = a1;
        __syncthreads();
    }

    // GEMM1: xr[10][384] @ W0[384][256] * S0 + B0 -> hs[10][256]
    {
        const int c = t;
        float acc[10];
#pragma unroll
        for (int r = 0; r < 10; ++r) acc[r] = 0.f;
        const float* Wc = W0 + c;
        for (int k = 0; k < 3 * NF; ++k) {
            const float wv = Wc[(size_t)k * (2 * NF)];
#pragma unroll
            for (int r = 0; r < 10; ++r) acc[r] = fmaf(xr[r][k], wv, acc[r]);
        }
        const float sc = S0[c], bb = B0[c];
#pragma unroll
        for (int r = 0; r < 10; ++r) {
            float v = acc[r] * sc + bb;
            hs[r][c] = (v >= 0.f) ? v : ALPHA * v;
        }
    }
    __syncthreads();

    // GEMM2: hs[10][256] @ W1[256][128] * S1 + B1 -> out (k split in halves)
    {
        const int c = t & 127, half = t >> 7;
        float acc[10];
#pragma unroll
        for (int r = 0; r < 10; ++r) acc[r] = 0.f;
        const float* Wc = W1 + c;
        for (int k = half * 128; k < half * 128 + 128; ++k) {
            const float wv = Wc[(size_t)k * NF];
#pragma unroll
            for (int r = 0; r < 10; ++r) acc[r] = fmaf(hs[r][k], wv, acc[r]);
        }
        float* part = &xr[0][0];   // reuse xr as [2][10][128] scratch
#pragma unroll
        for (int r = 0; r < 10; ++r) part[(half * 10 + r) * 128 + c] = acc[r];
        __syncthreads();
        if (half == 0) {
            const float sc = S1[c], bb = B1[c];
#pragma unroll
            for (int r = 0; r < 10; ++r) {
                float v = (part[r * 128 + c] + part[(10 + r) * 128 + c]) * sc + bb;
                v = (v >= 0.f) ? v : ALPHA * v;
                out[((size_t)b * N + m0 + r) * NF + c] = v;
            }
        }
    }
}

// ---------------------------------------------------------------------------
// Prefetch a layer's ks=0 B-fragments (issued before the preceding barrier).
// ---------------------------------------------------------------------------
template <int K, int NT>
__device__ __forceinline__ void load_bv0(const unsigned short* __restrict__ Wf,
                                         int lane, int wave, short8* bv) {
    constexpr int KS = K / 32;
#pragma unroll
    for (int n = 0; n < NT; ++n)
        bv[n] = *(const short8*)(Wf + (((size_t)(wave * NT + n) * KS) * 64 + lane) * 8);
}

// ---------------------------------------------------------------------------
// MFMA MLP layer, fragment-major LDS both sides.
// LDS tile = array of 1KiB fragments: frag(m,ks) at (m*KS+ks)*1024, lane-linear
// (lane l: pair m*16+(l&15), channels ks*32+(l>>4)*8..+7).
// Swapped MFMA: D = W x h^T -> lane holds 4 consecutive channels of one pair.
// Bias pre-loaded into accumulator (MFMA C-in).
// ---------------------------------------------------------------------------
template <int K, int COUT, int NT, int MT>
__device__ __forceinline__ void layer_mfma(const unsigned short* in,
                                           unsigned short* out,
                                           const unsigned short* __restrict__ Wf,
                                           const float* __restrict__ Bb,
                                           int lane, int wave, const short8* bv0) {
    constexpr int KS  = K / 32;
    constexpr int KSo = COUT / 32;
    const int r16 = lane & 15, g = lane >> 4;
    f32x4 acc[MT][NT];
#pragma unroll
    for (int n = 0; n < NT; ++n) {
        const f32x4 binit = *(const f32x4*)(Bb + (wave * NT + n) * 16 + g * 4);
#pragma unroll
        for (int m = 0; m < MT; ++m) acc[m][n] = binit;
    }
    const unsigned short* inL = in + lane * 8;  // +16B per lane
#pragma unroll
    for (int ks = 0; ks < KS; ++ks) {
        short8 av[MT];
#pragma unroll
        for (int m = 0; m < MT; ++m)
            av[m] = *(const short8*)(inL + (m * KS + ks) * 512);  // imm offset
        short8 bv[NT];
#pragma unroll
        for (int n = 0; n < NT; ++n) {
            if (ks == 0) bv[n] = bv0[n];
            else bv[n] = *(const short8*)(Wf + (((size_t)(wave * NT + n) * KS + ks) * 64 + lane) * 8);
        }
#pragma unroll
        for (int m = 0; m < MT; ++m)
#pragma unroll
            for (int n = 0; n < NT; ++n)
                acc[m][n] = __builtin_amdgcn_mfma_f32_16x16x32_bf16(
                    bv[n], av[m], acc[m][n], 0, 0, 0);
    }
    // epilogue: lane holds channels c0..c0+3 of pair p=m*16+r16,
    // c0 = (wave*NT+n)*16 + g*4 -> consumer frag (m*KSo + c0/32), slot:
    const int voff = (g >> 1) * 256 + r16 * 16 + (g & 1) * 8;  // per-lane bytes
#pragma unroll
    for (int n = 0; n < NT; ++n) {
        const int W16 = wave * NT + n;
        const int cbase = (W16 >> 1) * 1024 + (W16 & 1) * 512;
#pragma unroll
        for (int m = 0; m < MT; ++m) {
            float v0 = acc[m][n][0]; v0 = fmaxf(v0, ALPHA * v0);
            float v1 = acc[m][n][1]; v1 = fmaxf(v1, ALPHA * v1);
            float v2 = acc[m][n][2]; v2 = fmaxf(v2, ALPHA * v2);
            float v3 = acc[m][n][3]; v3 = fmaxf(v3, ALPHA * v3);
            uint2 w;
            w.x = cvt_pk(v0, v1);
            w.y = cvt_pk(v2, v3);
            *(uint2*)((char*)out + m * (KSo * 1024) + cbase + voff) = w;
        }
    }
}

// ---------------------------------------------------------------------------
// Kernel C: fused pairwise-difference MLP (bf16 MFMA) -> sim[b,i,j]
// 512 threads = 8 waves, 80 pairs; fragment-major 40KiB ping-pong LDS.
// ---------------------------------------------------------------------------
__global__ __launch_bounds__(512, 4) void k_pair_mlp_mfma(
    const float* __restrict__ nf,
    const unsigned short* __restrict__ W0f, const float* __restrict__ Bb0,
    const unsigned short* __restrict__ W1f, const float* __restrict__ Bb1,
    const unsigned short* __restrict__ W2f, const float* __restrict__ Bb2,
    const unsigned short* __restrict__ W3f, const float* __restrict__ Bb3,
    const float* __restrict__ Wout, const float* __restrict__ boutp,
    float* __restrict__ sim) {
    __shared__ unsigned short bufA[PT * 256];  // 40 KiB (40 fragments max)
    __shared__ unsigned short bufB[PT * 256];  // 40 KiB
    const int t = threadIdx.x;
    const int lane = t & 63, wave = t >> 6;
    const int tile0 = blockIdx.x * PT;

    // Stage h0 = |nf_i - nf_j| fragment-major: 20 frags (5 m-tiles x KS=4)
    for (int f = wave; f < 20; f += 8) {
        const int m = f >> 2, ks = f & 3;
        const int p = m * 16 + (lane & 15);
        const int P = tile0 + p;
        const int b = P / NN;
        const int r = P - b * NN;
        const int i = r / N, jj = r - i * N;
        const int ch0 = ks * 32 + (lane >> 4) * 8;
        const float4* fi = (const float4*)(nf + ((size_t)(b * N + i)) * NF + ch0);
        const float4* fj = (const float4*)(nf + ((size_t)(b * N + jj)) * NF + ch0);
        const float4 a0 = fi[0], a1 = fi[1];
        const float4 c0 = fj[0], c1 = fj[1];
        uint4 o;
        o.x = cvt_pk(fabsf(a0.x - c0.x), fabsf(a0.y - c0.y));
        o.y = cvt_pk(fabsf(a0.z - c0.z), fabsf(a0.w - c0.w));
        o.z = cvt_pk(fabsf(a1.x - c1.x), fabsf(a1.y - c1.y));
        o.w = cvt_pk(fabsf(a1.z - c1.z), fabsf(a1.w - c1.w));
        *(uint4*)((char*)bufA + f * 1024 + lane * 16) = o;
    }
    short8 bvp[2];
    load_bv0<128, 2>(W0f, lane, wave, bvp);
    __syncthreads();
    layer_mfma<128, 256, 2, 5>(bufA, bufB, W0f, Bb0, lane, wave, bvp);
    load_bv0<256, 2>(W1f, lane, wave, bvp);
    __syncthreads();
    layer_mfma<256, 256, 2, 5>(bufB, bufA, W1f, Bb1, lane, wave, bvp);
    load_bv0<256, 1>(W2f, lane, wave, bvp);
    __syncthreads();
    layer_mfma<256, 128, 1, 5>(bufA, bufB, W2f, Bb2, lane, wave, bvp);
    load_bv0<128, 1>(W3f, lane, wave, bvp);
    __syncthreads();
    layer_mfma<128, 128, 1, 5>(bufB, bufA, W3f, Bb3, lane, wave, bvp);
    __syncthreads();

    // sim = sigmoid(h @ Wout + bout), h in bufA fragment-major (KS=4)
    {
        const int p0 = t >> 3, q3 = t & 7;
        for (int pp = p0; pp < PT; pp += 64) {
            float acc = 0.f;
#pragma unroll
            for (int u = 0; u < 2; ++u) {
                const int c = q3 * 16 + u * 8;
                const int ksf = c >> 5;
                const int hi = (c & 31) >> 3;
                const int byte = ((pp >> 4) * 4 + ksf) * 1024 + (hi * 16 + (pp & 15)) * 16;
                const short8 hv = *(const short8*)((const char*)bufA + byte);
                const float* wp = Wout + c;
#pragma unroll
                for (int d = 0; d < 8; ++d)
                    acc = fmaf(bf2f((unsigned short)hv[d]), wp[d], acc);
            }
            acc += __shfl_xor(acc, 1);
            acc += __shfl_xor(acc, 2);
            acc += __shfl_xor(acc, 4);
            if (q3 == 0) {
                const float v = acc + boutp[0];
                sim[tile0 + pp] = 1.f / (1.f + expf(-v));
            }
        }
    }
}

// ---------------------------------------------------------------------------
// Kernel D: edge update given sim (row-local; safe in place)
// ---------------------------------------------------------------------------
__global__ void k_edge_update(const float* __restrict__ ef_in,
                              const float* __restrict__ sim,
                              float* __restrict__ ef_out) {
    const int b = blockIdx.x / N;
    const int i = blockIdx.x - b * N;
    const int t = threadIdx.x;  // 128 threads

    __shared__ float r0[128], r1[128], r2[128], r3[128];

    float e0 = 0.f, e1 = 0.f, s = 0.f;
    if (t < N) {
        e0 = ef_in[((size_t)(b * 2 + 0) * N + i) * N + t];
        e1 = ef_in[((size_t)(b * 2 + 1) * N + i) * N + t];
        if (t == i) { e0 = 0.f; e1 = 0.f; }
        s = sim[(size_t)(b * N + i) * N + t];
    }
    float f0 = e0 * s;
    float f1 = e1 * (1.f - s);
    r0[t] = e0; r1[t] = e1; r2[t] = fabsf(f0); r3[t] = fabsf(f1);
    __syncthreads();
    for (int st = 64; st > 0; st >>= 1) {
        if (t < st) {
            r0[t] += r0[t + st];
            r1[t] += r1[t + st];
            r2[t] += r2[t + st];
            r3[t] += r3[t + st];
        }
        __syncthreads();
    }
    const float m0 = r0[0], m1 = r1[0], n0 = r2[0], n1 = r3[0];
    if (t < N) {
        f0 = (n0 == 0.f) ? 0.f : (f0 / n0) * m0;
        f1 = (n1 == 0.f) ? 0.f : (f1 / n1) * m1;
        if (t == i) f0 += 1.f;
        f0 += 1e-6f;
        f1 += 1e-6f;
        const float inv = 1.f / (f0 + f1);
        ef_out[((size_t)(b * 2 + 0) * N + i) * N + t] = f0 * inv;
        ef_out[((size_t)(b * 2 + 1) * N + i) * N + t] = f1 * inv;
    }
}

// ---------------------------------------------------------------------------
extern "C" void kernel_launch(void* const* d_in, const int* in_sizes, int n_in,
                              void* d_out, int out_size, void* d_ws, size_t ws_size,
                              hipStream_t stream) {
    (void)in_sizes; (void)n_in; (void)out_size; (void)ws_size;

    const float* node_feat = (const float*)d_in[0];
    const float* edge_feat = (const float*)d_in[1];
    const float* nW0 = (const float*)d_in[2];
    const float* nS0 = (const float*)d_in[3];
    const float* nB0 = (const float*)d_in[4];
    const float* nW1 = (const float*)d_in[5];
    const float* nS1 = (const float*)d_in[6];
    const float* nB1 = (const float*)d_in[7];
    const float* eW0 = (const float*)d_in[8];
    const float* eS0 = (const float*)d_in[9];
    const float* eB0 = (const float*)d_in[10];
    const float* eW1 = (const float*)d_in[11];
    const float* eS1 = (const float*)d_in[12];
    const float* eB1 = (const float*)d_in[13];
    const float* eW2 = (const float*)d_in[14];
    const float* eS2 = (const float*)d_in[15];
    const float* eB2 = (const float*)d_in[16];
    const float* eW3 = (const float*)d_in[17];
    const float* eS3 = (const float*)d_in[18];
    const float* eB3 = (const float*)d_in[19];
    const float* eWout = (const float*)d_in[20];
    const float* eBout = (const float*)d_in[21];

    float* ws     = (float*)d_ws;
    float* nf_a   = ws;                               // B*N*NF
    float* nf_b   = nf_a + (size_t)B * N * NF;        // B*N*NF
    float* ef_ws  = nf_b + (size_t)B * N * NF;        // B*2*N*N
    float* simbuf = ef_ws + (size_t)B * 2 * N * N;    // B*N*N
    unsigned short* w0t = (unsigned short*)(simbuf + (size_t)B * N * N);
    unsigned short* w1t = w0t + (size_t)L * 256 * 128;   // fragment-ordered
    unsigned short* w2t = w1t + (size_t)L * 256 * 256;
    unsigned short* w3t = w2t + (size_t)L * 128 * 256;
    // total ws ~14 MB

    // --- weight prep (bf16, fragment-ordered, S folded) ---
    k_wprep_frag<<<(L * 128 * 256 + 255) / 256, 256, 0, stream>>>(eW0, eS0, w0t, 128, 256);
    k_wprep_frag<<<(L * 256 * 256 + 255) / 256, 256, 0, stream>>>(eW1, eS1, w1t, 256, 256);
    k_wprep_frag<<<(L * 256 * 128 + 255) / 256, 256, 0, stream>>>(eW2, eS2, w2t, 256, 128);
    k_wprep_frag<<<(L * 128 * 128 + 255) / 256, 256, 0, stream>>>(eW3, eS3, w3t, 128, 128);

    const float* nf_cur = node_feat;
    const float* ef_cur = edge_feat;
    float* nf_next_buf[3] = {nf_a, nf_b, nf_a};

    for (int l = 0; l < L; ++l) {
        // ---- node update (fused: aggr + 2 affine layers) ----
        k_node_fused<<<B * N / 10, 256, 0, stream>>>(
            nf_cur, ef_cur,
            nW0 + (size_t)l * 3 * NF * 2 * NF, nS0 + l * 2 * NF, nB0 + l * 2 * NF,
            nW1 + (size_t)l * 2 * NF * NF,     nS1 + l * NF,     nB1 + l * NF,
            nf_next_buf[l]);
        nf_cur = nf_next_buf[l];

        // ---- edge update: pairwise MLP via MFMA ----
        k_pair_mlp_mfma<<<NPAIR / PT, 512, 0, stream>>>(
            nf_cur,
            w0t + (size_t)l * 256 * 128, eB0 + l * 256,
            w1t + (size_t)l * 256 * 256, eB1 + l * 256,
            w2t + (size_t)l * 128 * 256, eB2 + l * 128,
            w3t + (size_t)l * 128 * 128, eB3 + l * 128,
            eWout + (size_t)l * 128, eBout + l, simbuf);

        float* ef_out = (l == L - 1) ? (float*)d_out : ef_ws;
        k_edge_update<<<B * N, 128, 0, stream>>>(ef_cur, simbuf, ef_out);
        ef_cur = ef_out;
    }
}